// Round 2
// baseline (3749.175 us; speedup 1.0000x reference)
//
#include <hip/hip_runtime.h>
#include <math.h>

#define PLANE (512*512)

__device__ __forceinline__ float gelu_f(float x) {
    return 0.5f * x * (1.0f + erff(x * 0.70710678118654752440f));
}

// ---------------- K1: LayerNorm over channels (64) ----------------
__global__ __launch_bounds__(128) void k_ln(const float* __restrict__ sc,
                                            const float* __restrict__ lnw,
                                            const float* __restrict__ lnb,
                                            float* __restrict__ sn) {
    __shared__ float tile[64 * 128];
    int tid = threadIdx.x;
    int p = blockIdx.x * 128 + tid;       // 0 .. 524287
    int b = p >> 18;
    int hw = p & (PLANE - 1);
    const float* src = sc + (size_t)b * 64 * PLANE + hw;
    float sum = 0.f, sq = 0.f;
    #pragma unroll 8
    for (int c = 0; c < 64; ++c) {
        float v = src[(size_t)c * PLANE];
        tile[c * 128 + tid] = v;
        sum += v; sq += v * v;
    }
    float mu = sum * (1.0f / 64.0f);
    float var = sq * (1.0f / 64.0f) - mu * mu;
    float rstd = rsqrtf(var + 1e-5f);
    float* dst = sn + (size_t)b * 64 * PLANE + hw;
    #pragma unroll 8
    for (int c = 0; c < 64; ++c) {
        float v = tile[c * 128 + tid];
        dst[(size_t)c * PLANE] = (v - mu) * rstd * lnw[c] + lnb[c];
    }
}

// ---------------- K2: depthwise 3x3 (64ch) + BN + GELU ----------------
__global__ __launch_bounds__(256) void k_dw64(const float* __restrict__ in,
                                              const float* __restrict__ wt,
                                              const float* __restrict__ bns,
                                              const float* __restrict__ bnt,
                                              float* __restrict__ out) {
    int idx = blockIdx.x * 256 + threadIdx.x;   // over 2*64*PLANE
    int w = idx & 511;
    int h = (idx >> 9) & 511;
    int bc = idx >> 18;
    int c = bc & 63;
    const float* ip = in + (size_t)bc * PLANE;
    const float* wp = wt + c * 9;
    float acc = 0.f;
    #pragma unroll
    for (int dh = -1; dh <= 1; ++dh) {
        int hh = h + dh; if (hh < 0 || hh > 511) continue;
        #pragma unroll
        for (int dw = -1; dw <= 1; ++dw) {
            int ww = w + dw; if (ww < 0 || ww > 511) continue;
            acc += wp[(dh + 1) * 3 + (dw + 1)] * ip[hh * 512 + ww];
        }
    }
    out[idx] = gelu_f(acc * bns[c] + bnt[c]);
}

// ---------------- K3: per-pixel pw 64->128 (+gelu) -> split; v = bn(pw 64->128) ----------------
__global__ __launch_bounds__(256) void k_pw_kv(const float* __restrict__ t1,
                                               const float* __restrict__ W1,
                                               const float* __restrict__ b1,
                                               const float* __restrict__ W2,
                                               const float* __restrict__ vbs,
                                               const float* __restrict__ vbt,
                                               float* __restrict__ k_in,
                                               float* __restrict__ v) {
    __shared__ float Wl[128 * 64];
    __shared__ float pb[128], ps[128], pt[128];
    int tid = threadIdx.x;
    int p = blockIdx.x * 256 + tid;
    int b = p >> 18;
    int hw = p & (PLANE - 1);
    for (int i = tid; i < 8192; i += 256) Wl[i] = W1[i];
    if (tid < 128) { pb[tid] = b1[tid]; ps[tid] = vbs[tid]; pt[tid] = vbt[tid]; }
    float t1r[64];
    const float* tp = t1 + (size_t)b * 64 * PLANE + hw;
    #pragma unroll
    for (int i = 0; i < 64; ++i) t1r[i] = tp[(size_t)i * PLANE];
    __syncthreads();
    float vin[64];
    float* kp = k_in + (size_t)b * 64 * PLANE + hw;
    for (int o = 0; o < 128; ++o) {
        float acc = pb[o];
        const float4* wr = (const float4*)&Wl[o * 64];
        #pragma unroll
        for (int i4 = 0; i4 < 16; ++i4) {
            float4 wv = wr[i4];
            acc += wv.x * t1r[i4 * 4 + 0] + wv.y * t1r[i4 * 4 + 1]
                 + wv.z * t1r[i4 * 4 + 2] + wv.w * t1r[i4 * 4 + 3];
        }
        float g = gelu_f(acc);
        if (o < 64) kp[(size_t)o * PLANE] = g;
        else        vin[o - 64] = g;
    }
    __syncthreads();
    for (int i = tid; i < 8192; i += 256) Wl[i] = W2[i];
    __syncthreads();
    float* vp = v + (size_t)b * 128 * PLANE + hw;
    for (int o = 0; o < 128; ++o) {
        float acc = 0.f;
        const float4* wr = (const float4*)&Wl[o * 64];
        #pragma unroll
        for (int i4 = 0; i4 < 16; ++i4) {
            float4 wv = wr[i4];
            acc += wv.x * vin[i4 * 4 + 0] + wv.y * vin[i4 * 4 + 1]
                 + wv.z * vin[i4 * 4 + 2] + wv.w * vin[i4 * 4 + 3];
        }
        vp[(size_t)o * PLANE] = acc * ps[o] + pt[o];
    }
}

// ---------------- K4/K5: grouped dw 3x3 (64->128) + BN + GELU, emit row/col pooled sums only ----------------
__global__ __launch_bounds__(512) void k_dwpool(const float* __restrict__ in,
                                                const float* __restrict__ wt,
                                                const float* __restrict__ bns,
                                                const float* __restrict__ bnt,
                                                float* __restrict__ rowsum,   // (B,128,512)
                                                float* __restrict__ colpart) { // (B,128,64,512)
    __shared__ float lred[2][8][8];
    int tid = threadIdx.x;
    int blk = blockIdx.x;            // (b*64+g)*64+hc
    int hc = blk & 63;
    int g  = (blk >> 6) & 63;
    int b  = blk >> 12;
    int o0 = 2 * g, o1 = 2 * g + 1;
    const float* ip = in + ((size_t)b * 64 + g) * PLANE;
    float w0[9], w1[9];
    #pragma unroll
    for (int k = 0; k < 9; ++k) { w0[k] = wt[o0 * 9 + k]; w1[k] = wt[o1 * 9 + k]; }
    float s0 = bns[o0], t0 = bnt[o0], s1 = bns[o1], tt1 = bnt[o1];
    int wx = tid;
    float ca0 = 0.f, ca1 = 0.f;
    int lane = tid & 63, wv = tid >> 6;
    for (int r = 0; r < 8; ++r) {
        int h = hc * 8 + r;
        float nb[9];
        #pragma unroll
        for (int dh = -1; dh <= 1; ++dh) {
            #pragma unroll
            for (int dw = -1; dw <= 1; ++dw) {
                int hh = h + dh, ww = wx + dw;
                nb[(dh + 1) * 3 + dw + 1] =
                    (hh >= 0 && hh < 512 && ww >= 0 && ww < 512) ? ip[hh * 512 + ww] : 0.f;
            }
        }
        float a0 = 0.f, a1 = 0.f;
        #pragma unroll
        for (int k = 0; k < 9; ++k) { a0 += w0[k] * nb[k]; a1 += w1[k] * nb[k]; }
        a0 = gelu_f(a0 * s0 + t0);
        a1 = gelu_f(a1 * s1 + tt1);
        ca0 += a0; ca1 += a1;
        #pragma unroll
        for (int off = 32; off > 0; off >>= 1) {
            a0 += __shfl_down(a0, off, 64);
            a1 += __shfl_down(a1, off, 64);
        }
        if (lane == 0) { lred[0][r][wv] = a0; lred[1][r][wv] = a1; }
    }
    colpart[(((size_t)b * 128 + o0) * 64 + hc) * 512 + wx] = ca0;
    colpart[(((size_t)b * 128 + o1) * 64 + hc) * 512 + wx] = ca1;
    __syncthreads();
    if (tid < 16) {
        int oo = tid >> 3, r = tid & 7;
        float s = 0.f;
        #pragma unroll
        for (int i = 0; i < 8; ++i) s += lred[oo][r][i];
        int och = oo == 0 ? o0 : o1;
        rowsum[((size_t)b * 128 + och) * 512 + hc * 8 + r] = s;
    }
}

// ---------------- v pooling: row/col sums of v ----------------
__global__ __launch_bounds__(512) void k_vpool(const float* __restrict__ v,
                                               float* __restrict__ rowsum,
                                               float* __restrict__ colpart) {
    __shared__ float lred[8][8];
    int tid = threadIdx.x;
    int blk = blockIdx.x;     // (b*128+c)*64+hc
    int hc = blk & 63;
    int bc = blk >> 6;
    const float* ip = v + (size_t)bc * PLANE;
    float ca = 0.f;
    int lane = tid & 63, wv = tid >> 6;
    for (int r = 0; r < 8; ++r) {
        float a = ip[(hc * 8 + r) * 512 + tid];
        ca += a;
        #pragma unroll
        for (int off = 32; off > 0; off >>= 1) a += __shfl_down(a, off, 64);
        if (lane == 0) lred[r][wv] = a;
    }
    colpart[((size_t)bc * 64 + hc) * 512 + tid] = ca;
    __syncthreads();
    if (tid < 8) {
        float s = 0.f;
        #pragma unroll
        for (int i = 0; i < 8; ++i) s += lred[tid][i];
        rowsum[(size_t)bc * 512 + hc * 8 + tid] = s;
    }
}

// ---------------- reduce col partials (64 chunks) ----------------
__global__ __launch_bounds__(256) void k_colreduce(const float* __restrict__ part,
                                                   float* __restrict__ out, int n) {
    int idx = blockIdx.x * 256 + threadIdx.x;
    if (idx >= n) return;
    int bc = idx >> 9, w = idx & 511;
    const float* pp = part + ((size_t)bc * 64) * 512 + w;
    float s = 0.f;
    #pragma unroll
    for (int p = 0; p < 64; ++p) s += pp[p * 512];
    out[idx] = s;
}

// ---------------- K6: axial attention (row & col), tiny ----------------
__global__ __launch_bounds__(256) void k_attn(const float* __restrict__ qrow,
                                              const float* __restrict__ krow,
                                              const float* __restrict__ vrow,
                                              const float* __restrict__ qcol,
                                              const float* __restrict__ kcol,
                                              const float* __restrict__ vcol,
                                              const float* __restrict__ perq,
                                              const float* __restrict__ perk,
                                              const float* __restrict__ pecq,
                                              const float* __restrict__ peck,
                                              float* __restrict__ arow,
                                              float* __restrict__ acol) {
    __shared__ float P[16][17];
    int blk = blockIdx.x;   // b*16 + head*2 + axis
    int axis = blk & 1;
    int head = (blk >> 1) & 7;
    int b = blk >> 4;
    const float* qs = axis ? qcol : qrow;
    const float* ks = axis ? kcol : krow;
    const float* vs = axis ? vcol : vrow;
    const float* peq = axis ? pecq : perq;
    const float* pek = axis ? peck : perk;
    float* out = axis ? acol : arow;
    int tid = threadIdx.x;
    int i = tid >> 4, j = tid & 15;
    int ci = head * 16 + i, cj = head * 16 + j;
    const float* qp = qs + ((size_t)b * 128 + ci) * 512;
    const float* kp = ks + ((size_t)b * 128 + cj) * 512;
    const float* qe = peq + ci * 512;
    const float* ke = pek + cj * 512;
    float s = 0.f;
    for (int n = 0; n < 512; ++n) {
        float qv = qp[n] * (1.f / 512.f) + qe[n];
        float kv = kp[n] * (1.f / 512.f) + ke[n];
        s += qv * kv;
    }
    s *= 0.0441941738241592203f;   // 1/sqrt(512)
    P[i][j] = s;
    __syncthreads();
    if (tid < 16) {
        float mx = -1e30f;
        #pragma unroll
        for (int jj = 0; jj < 16; ++jj) mx = fmaxf(mx, P[tid][jj]);
        float e[16];
        float sum = 0.f;
        #pragma unroll
        for (int jj = 0; jj < 16; ++jj) { e[jj] = expf(P[tid][jj] - mx); sum += e[jj]; }
        float inv = 1.f / sum;
        #pragma unroll
        for (int jj = 0; jj < 16; ++jj) P[tid][jj] = e[jj] * inv;
    }
    __syncthreads();
    for (int idx = tid; idx < 16 * 512; idx += 256) {
        int ii = idx >> 9, n = idx & 511;
        const float* vb = vs + ((size_t)b * 128 + head * 16) * 512 + n;
        float acc = 0.f;
        #pragma unroll
        for (int jj = 0; jj < 16; ++jj) acc += P[ii][jj] * vb[jj * 512] * (1.f / 512.f);
        out[((size_t)b * 128 + head * 16 + ii) * 512 + n] = acc;
    }
}

// ---------------- K7: fused shuffle + dw3x3(320) + GELU + pw 320->64 + GELU ----------------
__global__ __launch_bounds__(256) void k_proj(const float* __restrict__ x,
                                              const float* __restrict__ v,
                                              const float* __restrict__ arow,
                                              const float* __restrict__ acol,
                                              const float* __restrict__ aprw,
                                              const float* __restrict__ apcw,
                                              const float* __restrict__ dww,
                                              const float* __restrict__ dwb,
                                              const float* __restrict__ pww,
                                              const float* __restrict__ pwb,
                                              float* __restrict__ out) {
    __shared__ float pwT[160 * 64];   // 40 KB
    __shared__ float dwl[160 * 10];   // 6.4 KB
    int tid = threadIdx.x;
    int tx = tid & 15, ty = tid >> 4;
    int b = blockIdx.z;
    int w = blockIdx.x * 16 + tx;
    int h = blockIdx.y * 16 + ty;
    float acc[64];
    #pragma unroll
    for (int m = 0; m < 64; ++m) acc[m] = 0.f;
    const float* xb = x + (size_t)b * 64 * PLANE;
    const float* vb = v + (size_t)b * 128 * PLANE;
    const float* arb = arow + (size_t)b * 128 * 512;
    const float* acb = acol + (size_t)b * 128 * 512;
    for (int chunk = 0; chunk < 2; ++chunk) {
        __syncthreads();
        for (int idx = tid; idx < 160 * 64; idx += 256) {
            int sloc = idx >> 6, m = idx & 63;
            int src = chunk * 160 + sloc;
            int o = (src % 5) * 64 + (src / 5);     // shuffled-channel index fed by cat channel `src`
            pwT[idx] = pww[m * 320 + o];
        }
        for (int idx = tid; idx < 160; idx += 256) {
            int src = chunk * 160 + idx;
            int o = (src % 5) * 64 + (src / 5);
            #pragma unroll
            for (int k = 0; k < 9; ++k) dwl[idx * 10 + k] = dww[o * 9 + k];
            dwl[idx * 10 + 9] = dwb[o];
        }
        __syncthreads();
        for (int sloc = 0; sloc < 160; ++sloc) {
            int src = chunk * 160 + sloc;
            const float* ip;
            int mode = 0, c = 0;
            if (src < 64)       { ip = xb + (size_t)src * PLANE; }
            else if (src < 192) { c = src - 64;  ip = vb + (size_t)c * PLANE; mode = 1; }
            else                { c = src - 192; ip = vb + (size_t)c * PLANE; }
            float apr = 0.f, apc = 0.f;
            const float* arp = arb + (size_t)c * 512;
            const float* acp = acb + (size_t)c * 512;
            if (mode) { apr = aprw[c]; apc = apcw[c]; }
            float conv = dwl[sloc * 10 + 9];
            #pragma unroll
            for (int dh = -1; dh <= 1; ++dh) {
                int hh = h + dh; if (hh < 0 || hh > 511) continue;
                #pragma unroll
                for (int dw = -1; dw <= 1; ++dw) {
                    int ww2 = w + dw; if (ww2 < 0 || ww2 > 511) continue;
                    float val = ip[hh * 512 + ww2];
                    if (mode) val += apr * arp[ww2] + apc * acp[ww2];
                    conv += dwl[sloc * 10 + (dh + 1) * 3 + (dw + 1)] * val;
                }
            }
            float g = gelu_f(conv);
            const float4* pr = (const float4*)&pwT[sloc * 64];
            #pragma unroll
            for (int m4 = 0; m4 < 16; ++m4) {
                float4 wv = pr[m4];
                acc[m4 * 4 + 0] += wv.x * g;
                acc[m4 * 4 + 1] += wv.y * g;
                acc[m4 * 4 + 2] += wv.z * g;
                acc[m4 * 4 + 3] += wv.w * g;
            }
        }
    }
    float* op = out + (size_t)b * 64 * PLANE + h * 512 + w;
    #pragma unroll
    for (int m = 0; m < 64; ++m)
        op[(size_t)m * PLANE] = gelu_f(acc[m] + pwb[m]);
}

extern "C" void kernel_launch(void* const* d_in, const int* in_sizes, int n_in,
                              void* d_out, int out_size, void* d_ws, size_t ws_size,
                              hipStream_t stream) {
    const float* x    = (const float*)d_in[0];
    const float* sc   = (const float*)d_in[1];
    const float* lnw  = (const float*)d_in[2];
    const float* lnb  = (const float*)d_in[3];
    const float* ddw  = (const float*)d_in[4];
    const float* dbs  = (const float*)d_in[5];
    const float* dbt  = (const float*)d_in[6];
    const float* pw1  = (const float*)d_in[7];
    const float* pb1  = (const float*)d_in[8];
    const float* qdw  = (const float*)d_in[9];
    const float* qbs  = (const float*)d_in[10];
    const float* qbt  = (const float*)d_in[11];
    const float* kdw  = (const float*)d_in[12];
    const float* kbs  = (const float*)d_in[13];
    const float* kbt  = (const float*)d_in[14];
    const float* vpw  = (const float*)d_in[15];
    const float* vbs  = (const float*)d_in[16];
    const float* vbt  = (const float*)d_in[17];
    const float* pdw  = (const float*)d_in[18];
    const float* pdb  = (const float*)d_in[19];
    const float* ppw  = (const float*)d_in[20];
    const float* ppb  = (const float*)d_in[21];
    const float* perq = (const float*)d_in[22];
    const float* perk = (const float*)d_in[23];
    const float* pecq = (const float*)d_in[24];
    const float* peck = (const float*)d_in[25];
    const float* aprw = (const float*)d_in[26];
    const float* apcw = (const float*)d_in[27];

    // d_out doubles as scratch: sn (K1->K2), then k_in (K3->K4), then final out (K7).
    // Every element is fully rewritten before each read; deterministic across replays.
    float* bufA = (float*)d_out;         // 33,554,432 floats
    float* ws   = (float*)d_ws;
    float* bufB = ws;                    // 33,554,432 floats: t1, later col partials
    float* bufV = ws + 33554432;         // 67,108,864 floats: v
    float* sm   = ws + 100663296;        // pooled vectors (1,048,576 floats)
    float* qrow = sm;
    float* krow = sm + 131072;
    float* vrow = sm + 262144;
    float* qcol = sm + 393216;
    float* kcol = sm + 524288;
    float* vcol = sm + 655360;
    float* arow = sm + 786432;
    float* acol = sm + 917504;
    float* qcp  = bufB;                  // col partials alias dead t1 buffer
    float* kcp  = bufB + 8388608;
    float* vcp  = bufB + 16777216;

    k_ln   <<<4096,   128, 0, stream>>>(sc, lnw, lnb, bufA);
    k_dw64 <<<131072, 256, 0, stream>>>(bufA, ddw, dbs, dbt, bufB);
    k_pw_kv<<<2048,   256, 0, stream>>>(bufB, pw1, pb1, vpw, vbs, vbt, bufA, bufV);
    k_dwpool<<<8192,  512, 0, stream>>>(x,    qdw, qbs, qbt, qrow, qcp);
    k_dwpool<<<8192,  512, 0, stream>>>(bufA, kdw, kbs, kbt, krow, kcp);
    k_vpool<<<16384,  512, 0, stream>>>(bufV, vrow, vcp);
    k_colreduce<<<512, 256, 0, stream>>>(qcp, qcol, 131072);
    k_colreduce<<<512, 256, 0, stream>>>(kcp, kcol, 131072);
    k_colreduce<<<512, 256, 0, stream>>>(vcp, vcol, 131072);
    k_attn <<<32,     256, 0, stream>>>(qrow, krow, vrow, qcol, kcol, vcol,
                                        perq, perk, pecq, peck, arow, acol);
    dim3 g7(32, 32, 2);
    k_proj <<<g7,     256, 0, stream>>>(x, bufV, arow, acol, aprw, apcw,
                                        pdw, pdb, ppw, ppb, (float*)d_out);
}

// Round 3
// 3120.127 us; speedup vs baseline: 1.2016x; 1.2016x over previous
//
#include <hip/hip_runtime.h>
#include <math.h>

#define PLANE (512*512)

typedef short bf16x8 __attribute__((ext_vector_type(8)));
typedef float f32x4 __attribute__((ext_vector_type(4)));

__device__ __forceinline__ float gelu_f(float x) {
    return 0.5f * x * (1.0f + erff(x * 0.70710678118654752440f));
}

__device__ __forceinline__ unsigned short f2bf(float f) {
    union { float f; unsigned u; } v; v.f = f;
    unsigned r = v.u + 0x7FFFu + ((v.u >> 16) & 1u);
    return (unsigned short)(r >> 16);
}

// ---------------- K1: LayerNorm over channels (64) ----------------
__global__ __launch_bounds__(128) void k_ln(const float* __restrict__ sc,
                                            const float* __restrict__ lnw,
                                            const float* __restrict__ lnb,
                                            float* __restrict__ sn) {
    __shared__ float tile[64 * 128];
    int tid = threadIdx.x;
    int p = blockIdx.x * 128 + tid;       // 0 .. 524287
    int b = p >> 18;
    int hw = p & (PLANE - 1);
    const float* src = sc + (size_t)b * 64 * PLANE + hw;
    float sum = 0.f, sq = 0.f;
    #pragma unroll 8
    for (int c = 0; c < 64; ++c) {
        float v = src[(size_t)c * PLANE];
        tile[c * 128 + tid] = v;
        sum += v; sq += v * v;
    }
    float mu = sum * (1.0f / 64.0f);
    float var = sq * (1.0f / 64.0f) - mu * mu;
    float rstd = rsqrtf(var + 1e-5f);
    float* dst = sn + (size_t)b * 64 * PLANE + hw;
    #pragma unroll 8
    for (int c = 0; c < 64; ++c) {
        float v = tile[c * 128 + tid];
        dst[(size_t)c * PLANE] = (v - mu) * rstd * lnw[c] + lnb[c];
    }
}

// ---------------- K2: depthwise 3x3 (64ch) + BN + GELU ----------------
__global__ __launch_bounds__(256) void k_dw64(const float* __restrict__ in,
                                              const float* __restrict__ wt,
                                              const float* __restrict__ bns,
                                              const float* __restrict__ bnt,
                                              float* __restrict__ out) {
    int idx = blockIdx.x * 256 + threadIdx.x;   // over 2*64*PLANE
    int w = idx & 511;
    int h = (idx >> 9) & 511;
    int bc = idx >> 18;
    int c = bc & 63;
    const float* ip = in + (size_t)bc * PLANE;
    const float* wp = wt + c * 9;
    float acc = 0.f;
    #pragma unroll
    for (int dh = -1; dh <= 1; ++dh) {
        int hh = h + dh; if (hh < 0 || hh > 511) continue;
        #pragma unroll
        for (int dw = -1; dw <= 1; ++dw) {
            int ww = w + dw; if (ww < 0 || ww > 511) continue;
            acc += wp[(dh + 1) * 3 + (dw + 1)] * ip[hh * 512 + ww];
        }
    }
    out[idx] = gelu_f(acc * bns[c] + bnt[c]);
}

// ---------------- K3: per-pixel pw 64->128 (+gelu) -> split; v = bn(pw 64->128) ----------------
__global__ __launch_bounds__(256) void k_pw_kv(const float* __restrict__ t1,
                                               const float* __restrict__ W1,
                                               const float* __restrict__ b1,
                                               const float* __restrict__ W2,
                                               const float* __restrict__ vbs,
                                               const float* __restrict__ vbt,
                                               float* __restrict__ k_in,
                                               float* __restrict__ v) {
    __shared__ float Wl[128 * 64];
    __shared__ float pb[128], ps[128], pt[128];
    int tid = threadIdx.x;
    int p = blockIdx.x * 256 + tid;
    int b = p >> 18;
    int hw = p & (PLANE - 1);
    for (int i = tid; i < 8192; i += 256) Wl[i] = W1[i];
    if (tid < 128) { pb[tid] = b1[tid]; ps[tid] = vbs[tid]; pt[tid] = vbt[tid]; }
    float t1r[64];
    const float* tp = t1 + (size_t)b * 64 * PLANE + hw;
    #pragma unroll
    for (int i = 0; i < 64; ++i) t1r[i] = tp[(size_t)i * PLANE];
    __syncthreads();
    float vin[64];
    float* kp = k_in + (size_t)b * 64 * PLANE + hw;
    for (int o = 0; o < 128; ++o) {
        float acc = pb[o];
        const float4* wr = (const float4*)&Wl[o * 64];
        #pragma unroll
        for (int i4 = 0; i4 < 16; ++i4) {
            float4 wv = wr[i4];
            acc += wv.x * t1r[i4 * 4 + 0] + wv.y * t1r[i4 * 4 + 1]
                 + wv.z * t1r[i4 * 4 + 2] + wv.w * t1r[i4 * 4 + 3];
        }
        float g = gelu_f(acc);
        if (o < 64) kp[(size_t)o * PLANE] = g;
        else        vin[o - 64] = g;
    }
    __syncthreads();
    for (int i = tid; i < 8192; i += 256) Wl[i] = W2[i];
    __syncthreads();
    float* vp = v + (size_t)b * 128 * PLANE + hw;
    for (int o = 0; o < 128; ++o) {
        float acc = 0.f;
        const float4* wr = (const float4*)&Wl[o * 64];
        #pragma unroll
        for (int i4 = 0; i4 < 16; ++i4) {
            float4 wv = wr[i4];
            acc += wv.x * vin[i4 * 4 + 0] + wv.y * vin[i4 * 4 + 1]
                 + wv.z * vin[i4 * 4 + 2] + wv.w * vin[i4 * 4 + 3];
        }
        vp[(size_t)o * PLANE] = acc * ps[o] + pt[o];
    }
}

// ---------------- K4/K5: grouped dw 3x3 (64->128) + BN + GELU, emit row/col pooled sums only ----------------
__global__ __launch_bounds__(512) void k_dwpool(const float* __restrict__ in,
                                                const float* __restrict__ wt,
                                                const float* __restrict__ bns,
                                                const float* __restrict__ bnt,
                                                float* __restrict__ rowsum,   // (B,128,512)
                                                float* __restrict__ colpart) { // (B,128,64,512)
    __shared__ float lred[2][8][8];
    int tid = threadIdx.x;
    int blk = blockIdx.x;            // (b*64+g)*64+hc
    int hc = blk & 63;
    int g  = (blk >> 6) & 63;
    int b  = blk >> 12;
    int o0 = 2 * g, o1 = 2 * g + 1;
    const float* ip = in + ((size_t)b * 64 + g) * PLANE;
    float w0[9], w1[9];
    #pragma unroll
    for (int k = 0; k < 9; ++k) { w0[k] = wt[o0 * 9 + k]; w1[k] = wt[o1 * 9 + k]; }
    float s0 = bns[o0], t0 = bnt[o0], s1 = bns[o1], tt1 = bnt[o1];
    int wx = tid;
    float ca0 = 0.f, ca1 = 0.f;
    int lane = tid & 63, wv = tid >> 6;
    for (int r = 0; r < 8; ++r) {
        int h = hc * 8 + r;
        float nb[9];
        #pragma unroll
        for (int dh = -1; dh <= 1; ++dh) {
            #pragma unroll
            for (int dw = -1; dw <= 1; ++dw) {
                int hh = h + dh, ww = wx + dw;
                nb[(dh + 1) * 3 + dw + 1] =
                    (hh >= 0 && hh < 512 && ww >= 0 && ww < 512) ? ip[hh * 512 + ww] : 0.f;
            }
        }
        float a0 = 0.f, a1 = 0.f;
        #pragma unroll
        for (int k = 0; k < 9; ++k) { a0 += w0[k] * nb[k]; a1 += w1[k] * nb[k]; }
        a0 = gelu_f(a0 * s0 + t0);
        a1 = gelu_f(a1 * s1 + tt1);
        ca0 += a0; ca1 += a1;
        #pragma unroll
        for (int off = 32; off > 0; off >>= 1) {
            a0 += __shfl_down(a0, off, 64);
            a1 += __shfl_down(a1, off, 64);
        }
        if (lane == 0) { lred[0][r][wv] = a0; lred[1][r][wv] = a1; }
    }
    colpart[(((size_t)b * 128 + o0) * 64 + hc) * 512 + wx] = ca0;
    colpart[(((size_t)b * 128 + o1) * 64 + hc) * 512 + wx] = ca1;
    __syncthreads();
    if (tid < 16) {
        int oo = tid >> 3, r = tid & 7;
        float s = 0.f;
        #pragma unroll
        for (int i = 0; i < 8; ++i) s += lred[oo][r][i];
        int och = oo == 0 ? o0 : o1;
        rowsum[((size_t)b * 128 + och) * 512 + hc * 8 + r] = s;
    }
}

// ---------------- v pooling: row/col sums of v ----------------
__global__ __launch_bounds__(512) void k_vpool(const float* __restrict__ v,
                                               float* __restrict__ rowsum,
                                               float* __restrict__ colpart) {
    __shared__ float lred[8][8];
    int tid = threadIdx.x;
    int blk = blockIdx.x;     // (b*128+c)*64+hc
    int hc = blk & 63;
    int bc = blk >> 6;
    const float* ip = v + (size_t)bc * PLANE;
    float ca = 0.f;
    int lane = tid & 63, wv = tid >> 6;
    for (int r = 0; r < 8; ++r) {
        float a = ip[(hc * 8 + r) * 512 + tid];
        ca += a;
        #pragma unroll
        for (int off = 32; off > 0; off >>= 1) a += __shfl_down(a, off, 64);
        if (lane == 0) lred[r][wv] = a;
    }
    colpart[((size_t)bc * 64 + hc) * 512 + tid] = ca;
    __syncthreads();
    if (tid < 8) {
        float s = 0.f;
        #pragma unroll
        for (int i = 0; i < 8; ++i) s += lred[tid][i];
        rowsum[(size_t)bc * 512 + hc * 8 + tid] = s;
    }
}

// ---------------- reduce col partials (64 chunks) ----------------
__global__ __launch_bounds__(256) void k_colreduce(const float* __restrict__ part,
                                                   float* __restrict__ out, int n) {
    int idx = blockIdx.x * 256 + threadIdx.x;
    if (idx >= n) return;
    int bc = idx >> 9, w = idx & 511;
    const float* pp = part + ((size_t)bc * 64) * 512 + w;
    float s = 0.f;
    #pragma unroll
    for (int p = 0; p < 64; ++p) s += pp[p * 512];
    out[idx] = s;
}

// ---------------- K6: axial attention (row & col), tiny ----------------
__global__ __launch_bounds__(256) void k_attn(const float* __restrict__ qrow,
                                              const float* __restrict__ krow,
                                              const float* __restrict__ vrow,
                                              const float* __restrict__ qcol,
                                              const float* __restrict__ kcol,
                                              const float* __restrict__ vcol,
                                              const float* __restrict__ perq,
                                              const float* __restrict__ perk,
                                              const float* __restrict__ pecq,
                                              const float* __restrict__ peck,
                                              float* __restrict__ arow,
                                              float* __restrict__ acol) {
    __shared__ float P[16][17];
    int blk = blockIdx.x;   // b*16 + head*2 + axis
    int axis = blk & 1;
    int head = (blk >> 1) & 7;
    int b = blk >> 4;
    const float* qs = axis ? qcol : qrow;
    const float* ks = axis ? kcol : krow;
    const float* vs = axis ? vcol : vrow;
    const float* peq = axis ? pecq : perq;
    const float* pek = axis ? peck : perk;
    float* out = axis ? acol : arow;
    int tid = threadIdx.x;
    int i = tid >> 4, j = tid & 15;
    int ci = head * 16 + i, cj = head * 16 + j;
    const float* qp = qs + ((size_t)b * 128 + ci) * 512;
    const float* kp = ks + ((size_t)b * 128 + cj) * 512;
    const float* qe = peq + ci * 512;
    const float* ke = pek + cj * 512;
    float s = 0.f;
    for (int n = 0; n < 512; ++n) {
        float qv = qp[n] * (1.f / 512.f) + qe[n];
        float kv = kp[n] * (1.f / 512.f) + ke[n];
        s += qv * kv;
    }
    s *= 0.0441941738241592203f;   // 1/sqrt(512)
    P[i][j] = s;
    __syncthreads();
    if (tid < 16) {
        float mx = -1e30f;
        #pragma unroll
        for (int jj = 0; jj < 16; ++jj) mx = fmaxf(mx, P[tid][jj]);
        float e[16];
        float sum = 0.f;
        #pragma unroll
        for (int jj = 0; jj < 16; ++jj) { e[jj] = expf(P[tid][jj] - mx); sum += e[jj]; }
        float inv = 1.f / sum;
        #pragma unroll
        for (int jj = 0; jj < 16; ++jj) P[tid][jj] = e[jj] * inv;
    }
    __syncthreads();
    for (int idx = tid; idx < 16 * 512; idx += 256) {
        int ii = idx >> 9, n = idx & 511;
        const float* vb = vs + ((size_t)b * 128 + head * 16) * 512 + n;
        float acc = 0.f;
        #pragma unroll
        for (int jj = 0; jj < 16; ++jj) acc += P[ii][jj] * vb[jj * 512] * (1.f / 512.f);
        out[((size_t)b * 128 + head * 16 + ii) * 512 + n] = acc;
    }
}

// ---------------- setup: shuffled pw weights -> bf16 ----------------
__global__ __launch_bounds__(256) void k_wsetup(const float* __restrict__ pww,
                                                unsigned short* __restrict__ wsh) {
    int tid = blockIdx.x * 256 + threadIdx.x;
    if (tid >= 64 * 320) return;
    int m = tid / 320, src = tid % 320;
    int o = (src % 5) * 64 + src / 5;     // shuffled-channel index fed by cat channel `src`
    wsh[m * 320 + src] = f2bf(pww[m * 320 + o]);
}

// ---------------- K7: fused shuffle + dw3x3(320) + GELU + MFMA pw 320->64 + GELU ----------------
// One block = 1 row x 64 cols of output. Phase 1: stage conv inputs in LDS
// (8 chunks of 24 planes), compute 320 dw-conv+GELU values per pixel into
// bf16 Bt tile. Phase 2: 16x16x32 bf16 MFMA GEMM 320 -> 64 with fused epilogue.
__global__ __launch_bounds__(256) void k_proj2(
    const float* __restrict__ x, const float* __restrict__ v,
    const float* __restrict__ arow, const float* __restrict__ acol,
    const float* __restrict__ aprw, const float* __restrict__ apcw,
    const float* __restrict__ dww, const float* __restrict__ dwb,
    const unsigned short* __restrict__ wsh, const float* __restrict__ pwb,
    float* __restrict__ out)
{
    __shared__ float stage[24][3][67];      // 19,296 B
    __shared__ unsigned short Bt[64][328];  // 41,984 B (row = 656 B, 16B-aligned)
    int tid = threadIdx.x;
    int lane = tid & 63, wva = tid >> 6;
    int w0 = blockIdx.x * 64;
    int h  = blockIdx.y;
    int b  = blockIdx.z;
    const float* xb = x + (size_t)b * 64 * PLANE;
    const float* vb = v + (size_t)b * 128 * PLANE;
    const float* arb = arow + (size_t)b * 128 * 512;
    const float* acb = acol + (size_t)b * 128 * 512;

    // A-fragments: wave wva owns m-tile wva (output rows wva*16 .. +16).
    // Layout for mfma_f32_16x16x32_bf16: A[row=lane&15][k=(lane>>4)*8+j].
    bf16x8 afrag[10];
    {
        const unsigned short* wp = wsh + (size_t)(wva * 16 + (lane & 15)) * 320 + ((lane >> 4) * 8);
        #pragma unroll
        for (int ks = 0; ks < 10; ++ks)
            afrag[ks] = *(const bf16x8*)(wp + ks * 32);
    }

    float vr0 = (h >= 1)   ? 1.f : 0.f;
    float vr2 = (h <= 510) ? 1.f : 0.f;

    for (int chunk = 0; chunk < 8; ++chunk) {
        int c0 = chunk * 24;
        __syncthreads();
        // stage 24 planes x 3 rows x 66 cols (zero-fill = conv zero padding)
        for (int i = tid; i < 24 * 198; i += 256) {
            int pl = i / 198;
            int rem = i - pl * 198;
            int rr = rem / 66, cc = rem - rr * 66;
            int plane = c0 + pl;
            int hh = h + rr - 1, ww = w0 + cc - 1;
            float val = 0.f;
            if (hh >= 0 && hh < 512 && ww >= 0 && ww < 512) {
                const float* sp = (plane < 64) ? (xb + (size_t)plane * PLANE)
                                               : (vb + (size_t)(plane - 64) * PLANE);
                val = sp[hh * 512 + ww];
            }
            stage[pl][rr][cc] = val;
        }
        __syncthreads();
        // pass A: plain conv (x channels -> src=plane, v channels -> src=192+c)
        for (int t = tid; t < 24 * 64; t += 256) {
            int pl = t >> 6, px = t & 63;
            int plane = c0 + pl;
            int src = (plane < 64) ? plane : (192 + plane - 64);
            int o = (src % 5) * 64 + src / 5;
            const float* wt = dww + o * 9;
            float conv = dwb[o];
            #pragma unroll
            for (int rr = 0; rr < 3; ++rr)
                #pragma unroll
                for (int dc = 0; dc < 3; ++dc)
                    conv += wt[rr * 3 + dc] * stage[pl][rr][px + dc];
            Bt[px][src] = f2bf(gelu_f(conv));
        }
        // pass B: attn conv (v channels -> src=64+c); attn map depends only on w'
        if (c0 + 24 > 64) {
            for (int t = tid; t < 24 * 64; t += 256) {
                int pl = t >> 6, px = t & 63;
                int plane = c0 + pl;
                if (plane < 64) continue;        // wave-uniform (pl uniform per wave)
                int c = plane - 64;
                int src = 64 + c;
                int o = (src % 5) * 64 + src / 5;
                const float* wt = dww + o * 9;
                float apr = aprw[c], apc = apcw[c];
                const float* arp = arb + (size_t)c * 512;
                const float* acp = acb + (size_t)c * 512;
                float conv = dwb[o];
                #pragma unroll
                for (int dc = 0; dc < 3; ++dc) {
                    int ww = w0 + px - 1 + dc;
                    float Aval = 0.f;
                    if (ww >= 0 && ww < 512) Aval = apr * arp[ww] + apc * acp[ww];
                    float wsum = wt[dc] * vr0 + wt[3 + dc] + wt[6 + dc] * vr2;
                    conv += Aval * wsum
                          + wt[dc]     * stage[pl][0][px + dc]
                          + wt[3 + dc] * stage[pl][1][px + dc]
                          + wt[6 + dc] * stage[pl][2][px + dc];
                }
                Bt[px][src] = f2bf(gelu_f(conv));
            }
        }
    }
    __syncthreads();

    // MFMA phase: D[64 m][64 px]; wave wva -> m-tile wva, 4 pixel tiles.
    f32x4 acc[4];
    #pragma unroll
    for (int pt = 0; pt < 4; ++pt) acc[pt] = (f32x4){0.f, 0.f, 0.f, 0.f};
    #pragma unroll
    for (int ks = 0; ks < 10; ++ks) {
        #pragma unroll
        for (int pt = 0; pt < 4; ++pt) {
            const bf16x8* bp = (const bf16x8*)&Bt[pt * 16 + (lane & 15)][ks * 32 + ((lane >> 4) * 8)];
            acc[pt] = __builtin_amdgcn_mfma_f32_16x16x32_bf16(afrag[ks], *bp, acc[pt], 0, 0, 0);
        }
    }
    // epilogue: D row=(lane>>4)*4+reg -> m, col=lane&15 -> pixel
    #pragma unroll
    for (int pt = 0; pt < 4; ++pt) {
        int px = pt * 16 + (lane & 15);
        #pragma unroll
        for (int r = 0; r < 4; ++r) {
            int m = wva * 16 + (lane >> 4) * 4 + r;
            out[((size_t)b * 64 + m) * PLANE + h * 512 + w0 + px] = gelu_f(acc[pt][r] + pwb[m]);
        }
    }
}

extern "C" void kernel_launch(void* const* d_in, const int* in_sizes, int n_in,
                              void* d_out, int out_size, void* d_ws, size_t ws_size,
                              hipStream_t stream) {
    const float* x    = (const float*)d_in[0];
    const float* sc   = (const float*)d_in[1];
    const float* lnw  = (const float*)d_in[2];
    const float* lnb  = (const float*)d_in[3];
    const float* ddw  = (const float*)d_in[4];
    const float* dbs  = (const float*)d_in[5];
    const float* dbt  = (const float*)d_in[6];
    const float* pw1  = (const float*)d_in[7];
    const float* pb1  = (const float*)d_in[8];
    const float* qdw  = (const float*)d_in[9];
    const float* qbs  = (const float*)d_in[10];
    const float* qbt  = (const float*)d_in[11];
    const float* kdw  = (const float*)d_in[12];
    const float* kbs  = (const float*)d_in[13];
    const float* kbt  = (const float*)d_in[14];
    const float* vpw  = (const float*)d_in[15];
    const float* vbs  = (const float*)d_in[16];
    const float* vbt  = (const float*)d_in[17];
    const float* pdw  = (const float*)d_in[18];
    const float* pdb  = (const float*)d_in[19];
    const float* ppw  = (const float*)d_in[20];
    const float* ppb  = (const float*)d_in[21];
    const float* perq = (const float*)d_in[22];
    const float* perk = (const float*)d_in[23];
    const float* pecq = (const float*)d_in[24];
    const float* peck = (const float*)d_in[25];
    const float* aprw = (const float*)d_in[26];
    const float* apcw = (const float*)d_in[27];

    // d_out doubles as scratch: sn (K1->K2), then k_in (K3->K4), then final out (K7).
    float* bufA = (float*)d_out;         // 33,554,432 floats
    float* ws   = (float*)d_ws;
    float* bufB = ws;                    // 33,554,432 floats: t1, later col partials
    float* bufV = ws + 33554432;         // 67,108,864 floats: v
    float* sm   = ws + 100663296;        // pooled vectors (1,048,576 floats)
    float* qrow = sm;
    float* krow = sm + 131072;
    float* vrow = sm + 262144;
    float* qcol = sm + 393216;
    float* kcol = sm + 524288;
    float* vcol = sm + 655360;
    float* arow = sm + 786432;
    float* acol = sm + 917504;
    unsigned short* wsh = (unsigned short*)(ws + 101711872);   // 20480 bf16
    float* qcp  = bufB;                  // col partials alias dead t1 buffer
    float* kcp  = bufB + 8388608;
    float* vcp  = bufB + 16777216;

    k_wsetup<<<80,    256, 0, stream>>>(ppw, wsh);
    k_ln   <<<4096,   128, 0, stream>>>(sc, lnw, lnb, bufA);
    k_dw64 <<<131072, 256, 0, stream>>>(bufA, ddw, dbs, dbt, bufB);
    k_pw_kv<<<2048,   256, 0, stream>>>(bufB, pw1, pb1, vpw, vbs, vbt, bufA, bufV);
    k_dwpool<<<8192,  512, 0, stream>>>(x,    qdw, qbs, qbt, qrow, qcp);
    k_dwpool<<<8192,  512, 0, stream>>>(bufA, kdw, kbs, kbt, krow, kcp);
    k_vpool<<<16384,  512, 0, stream>>>(bufV, vrow, vcp);
    k_colreduce<<<512, 256, 0, stream>>>(qcp, qcol, 131072);
    k_colreduce<<<512, 256, 0, stream>>>(kcp, kcol, 131072);
    k_colreduce<<<512, 256, 0, stream>>>(vcp, vcol, 131072);
    k_attn <<<32,     256, 0, stream>>>(qrow, krow, vrow, qcol, kcol, vcol,
                                        perq, perk, pecq, peck, arow, acol);
    dim3 g7(8, 512, 2);
    k_proj2<<<g7,     256, 0, stream>>>(x, bufV, arow, acol, aprw, apcw,
                                        pdw, pdb, wsh, ppb, (float*)d_out);
}

// Round 5
// 2240.003 us; speedup vs baseline: 1.6737x; 1.3929x over previous
//
#include <hip/hip_runtime.h>
#include <math.h>

#define PLANE (512*512)

typedef short bf16x8 __attribute__((ext_vector_type(8)));
typedef float f32x4 __attribute__((ext_vector_type(4)));

// fast GELU: 0.5*x*(1+erf(x/sqrt(2))), erf via Abramowitz-Stegun 7.1.26 (|err|<=1.5e-7)
__device__ __forceinline__ float gelu_f(float x) {
    float ax = fabsf(x) * 0.70710678118654752440f;   // z = |x|/sqrt(2)
    float t = __builtin_amdgcn_rcpf(1.0f + 0.3275911f * ax);
    float poly = t * (0.254829592f + t * (-0.284496736f + t * (1.421413741f
               + t * (-1.453152027f + t * 1.061405429f))));
    float e = __expf(-ax * ax);
    float er = 1.0f - poly * e;
    er = copysignf(er, x);
    return 0.5f * x * (1.0f + er);
}

__device__ __forceinline__ unsigned short f2bf(float f) {
    union { float f; unsigned u; } v; v.f = f;
    unsigned r = v.u + 0x7FFFu + ((v.u >> 16) & 1u);
    return (unsigned short)(r >> 16);
}

// ---------------- K1: LayerNorm over channels (64) ----------------
__global__ __launch_bounds__(128) void k_ln(const float* __restrict__ sc,
                                            const float* __restrict__ lnw,
                                            const float* __restrict__ lnb,
                                            float* __restrict__ sn) {
    __shared__ float tile[64 * 128];
    int tid = threadIdx.x;
    int p = blockIdx.x * 128 + tid;       // 0 .. 524287
    int b = p >> 18;
    int hw = p & (PLANE - 1);
    const float* src = sc + (size_t)b * 64 * PLANE + hw;
    float sum = 0.f, sq = 0.f;
    #pragma unroll 8
    for (int c = 0; c < 64; ++c) {
        float v = src[(size_t)c * PLANE];
        tile[c * 128 + tid] = v;
        sum += v; sq += v * v;
    }
    float mu = sum * (1.0f / 64.0f);
    float var = sq * (1.0f / 64.0f) - mu * mu;
    float rstd = rsqrtf(var + 1e-5f);
    float* dst = sn + (size_t)b * 64 * PLANE + hw;
    #pragma unroll 8
    for (int c = 0; c < 64; ++c) {
        float v = tile[c * 128 + tid];
        dst[(size_t)c * PLANE] = (v - mu) * rstd * lnw[c] + lnb[c];
    }
}

// ---------------- K2: depthwise 3x3 (64ch) + BN + GELU ----------------
__global__ __launch_bounds__(256) void k_dw64(const float* __restrict__ in,
                                              const float* __restrict__ wt,
                                              const float* __restrict__ bns,
                                              const float* __restrict__ bnt,
                                              float* __restrict__ out) {
    int idx = blockIdx.x * 256 + threadIdx.x;   // over 2*64*PLANE
    int w = idx & 511;
    int h = (idx >> 9) & 511;
    int bc = idx >> 18;
    int c = bc & 63;
    const float* ip = in + (size_t)bc * PLANE;
    const float* wp = wt + c * 9;
    float acc = 0.f;
    #pragma unroll
    for (int dh = -1; dh <= 1; ++dh) {
        int hh = h + dh; if (hh < 0 || hh > 511) continue;
        #pragma unroll
        for (int dw = -1; dw <= 1; ++dw) {
            int ww = w + dw; if (ww < 0 || ww > 511) continue;
            acc += wp[(dh + 1) * 3 + (dw + 1)] * ip[hh * 512 + ww];
        }
    }
    out[idx] = gelu_f(acc * bns[c] + bnt[c]);
}

// ---------------- K3: per-pixel pw 64->128 (+gelu) -> split; v = bn(pw 64->128) ----------------
__global__ __launch_bounds__(256) void k_pw_kv(const float* __restrict__ t1,
                                               const float* __restrict__ W1,
                                               const float* __restrict__ b1,
                                               const float* __restrict__ W2,
                                               const float* __restrict__ vbs,
                                               const float* __restrict__ vbt,
                                               float* __restrict__ k_in,
                                               float* __restrict__ v) {
    __shared__ float Wl[128 * 64];
    __shared__ float pb[128], ps[128], pt[128];
    int tid = threadIdx.x;
    int p = blockIdx.x * 256 + tid;
    int b = p >> 18;
    int hw = p & (PLANE - 1);
    for (int i = tid; i < 8192; i += 256) Wl[i] = W1[i];
    if (tid < 128) { pb[tid] = b1[tid]; ps[tid] = vbs[tid]; pt[tid] = vbt[tid]; }
    float t1r[64];
    const float* tp = t1 + (size_t)b * 64 * PLANE + hw;
    #pragma unroll
    for (int i = 0; i < 64; ++i) t1r[i] = tp[(size_t)i * PLANE];
    __syncthreads();
    float vin[64];
    float* kp = k_in + (size_t)b * 64 * PLANE + hw;
    for (int o = 0; o < 128; ++o) {
        float acc = pb[o];
        const float4* wr = (const float4*)&Wl[o * 64];
        #pragma unroll
        for (int i4 = 0; i4 < 16; ++i4) {
            float4 wv = wr[i4];
            acc += wv.x * t1r[i4 * 4 + 0] + wv.y * t1r[i4 * 4 + 1]
                 + wv.z * t1r[i4 * 4 + 2] + wv.w * t1r[i4 * 4 + 3];
        }
        float g = gelu_f(acc);
        if (o < 64) kp[(size_t)o * PLANE] = g;
        else        vin[o - 64] = g;
    }
    __syncthreads();
    for (int i = tid; i < 8192; i += 256) Wl[i] = W2[i];
    __syncthreads();
    float* vp = v + (size_t)b * 128 * PLANE + hw;
    for (int o = 0; o < 128; ++o) {
        float acc = 0.f;
        const float4* wr = (const float4*)&Wl[o * 64];
        #pragma unroll
        for (int i4 = 0; i4 < 16; ++i4) {
            float4 wv = wr[i4];
            acc += wv.x * vin[i4 * 4 + 0] + wv.y * vin[i4 * 4 + 1]
                 + wv.z * vin[i4 * 4 + 2] + wv.w * vin[i4 * 4 + 3];
        }
        vp[(size_t)o * PLANE] = acc * ps[o] + pt[o];
    }
}

// ---------------- K4/K5: grouped dw 3x3 (64->128) + BN + GELU, emit row/col pooled sums only ----------------
__global__ __launch_bounds__(512) void k_dwpool(const float* __restrict__ in,
                                                const float* __restrict__ wt,
                                                const float* __restrict__ bns,
                                                const float* __restrict__ bnt,
                                                float* __restrict__ rowsum,   // (B,128,512)
                                                float* __restrict__ colpart) { // (B,128,64,512)
    __shared__ float lred[2][8][8];
    int tid = threadIdx.x;
    int blk = blockIdx.x;            // (b*64+g)*64+hc
    int hc = blk & 63;
    int g  = (blk >> 6) & 63;
    int b  = blk >> 12;
    int o0 = 2 * g, o1 = 2 * g + 1;
    const float* ip = in + ((size_t)b * 64 + g) * PLANE;
    float w0[9], w1[9];
    #pragma unroll
    for (int k = 0; k < 9; ++k) { w0[k] = wt[o0 * 9 + k]; w1[k] = wt[o1 * 9 + k]; }
    float s0 = bns[o0], t0 = bnt[o0], s1 = bns[o1], tt1 = bnt[o1];
    int wx = tid;
    float ca0 = 0.f, ca1 = 0.f;
    int lane = tid & 63, wv = tid >> 6;
    for (int r = 0; r < 8; ++r) {
        int h = hc * 8 + r;
        float nb[9];
        #pragma unroll
        for (int dh = -1; dh <= 1; ++dh) {
            #pragma unroll
            for (int dw = -1; dw <= 1; ++dw) {
                int hh = h + dh, ww = wx + dw;
                nb[(dh + 1) * 3 + dw + 1] =
                    (hh >= 0 && hh < 512 && ww >= 0 && ww < 512) ? ip[hh * 512 + ww] : 0.f;
            }
        }
        float a0 = 0.f, a1 = 0.f;
        #pragma unroll
        for (int k = 0; k < 9; ++k) { a0 += w0[k] * nb[k]; a1 += w1[k] * nb[k]; }
        a0 = gelu_f(a0 * s0 + t0);
        a1 = gelu_f(a1 * s1 + tt1);
        ca0 += a0; ca1 += a1;
        #pragma unroll
        for (int off = 32; off > 0; off >>= 1) {
            a0 += __shfl_down(a0, off, 64);
            a1 += __shfl_down(a1, off, 64);
        }
        if (lane == 0) { lred[0][r][wv] = a0; lred[1][r][wv] = a1; }
    }
    colpart[(((size_t)b * 128 + o0) * 64 + hc) * 512 + wx] = ca0;
    colpart[(((size_t)b * 128 + o1) * 64 + hc) * 512 + wx] = ca1;
    __syncthreads();
    if (tid < 16) {
        int oo = tid >> 3, r = tid & 7;
        float s = 0.f;
        #pragma unroll
        for (int i = 0; i < 8; ++i) s += lred[oo][r][i];
        int och = oo == 0 ? o0 : o1;
        rowsum[((size_t)b * 128 + och) * 512 + hc * 8 + r] = s;
    }
}

// ---------------- v pooling: row/col sums of v ----------------
__global__ __launch_bounds__(512) void k_vpool(const float* __restrict__ v,
                                               float* __restrict__ rowsum,
                                               float* __restrict__ colpart) {
    __shared__ float lred[8][8];
    int tid = threadIdx.x;
    int blk = blockIdx.x;     // (b*128+c)*64+hc
    int hc = blk & 63;
    int bc = blk >> 6;
    const float* ip = v + (size_t)bc * PLANE;
    float ca = 0.f;
    int lane = tid & 63, wv = tid >> 6;
    for (int r = 0; r < 8; ++r) {
        float a = ip[(hc * 8 + r) * 512 + tid];
        ca += a;
        #pragma unroll
        for (int off = 32; off > 0; off >>= 1) a += __shfl_down(a, off, 64);
        if (lane == 0) lred[r][wv] = a;
    }
    colpart[((size_t)bc * 64 + hc) * 512 + tid] = ca;
    __syncthreads();
    if (tid < 8) {
        float s = 0.f;
        #pragma unroll
        for (int i = 0; i < 8; ++i) s += lred[tid][i];
        rowsum[(size_t)bc * 512 + hc * 8 + tid] = s;
    }
}

// ---------------- reduce col partials (64 chunks) ----------------
__global__ __launch_bounds__(256) void k_colreduce(const float* __restrict__ part,
                                                   float* __restrict__ out, int n) {
    int idx = blockIdx.x * 256 + threadIdx.x;
    if (idx >= n) return;
    int bc = idx >> 9, w = idx & 511;
    const float* pp = part + ((size_t)bc * 64) * 512 + w;
    float s = 0.f;
    #pragma unroll
    for (int p = 0; p < 64; ++p) s += pp[p * 512];
    out[idx] = s;
}

// ---------------- K6: axial attention (row & col), tiny ----------------
__global__ __launch_bounds__(256) void k_attn(const float* __restrict__ qrow,
                                              const float* __restrict__ krow,
                                              const float* __restrict__ vrow,
                                              const float* __restrict__ qcol,
                                              const float* __restrict__ kcol,
                                              const float* __restrict__ vcol,
                                              const float* __restrict__ perq,
                                              const float* __restrict__ perk,
                                              const float* __restrict__ pecq,
                                              const float* __restrict__ peck,
                                              float* __restrict__ arow,
                                              float* __restrict__ acol) {
    __shared__ float P[16][17];
    int blk = blockIdx.x;   // b*16 + head*2 + axis
    int axis = blk & 1;
    int head = (blk >> 1) & 7;
    int b = blk >> 4;
    const float* qs = axis ? qcol : qrow;
    const float* ks = axis ? kcol : krow;
    const float* vs = axis ? vcol : vrow;
    const float* peq = axis ? pecq : perq;
    const float* pek = axis ? peck : perk;
    float* out = axis ? acol : arow;
    int tid = threadIdx.x;
    int i = tid >> 4, j = tid & 15;
    int ci = head * 16 + i, cj = head * 16 + j;
    const float* qp = qs + ((size_t)b * 128 + ci) * 512;
    const float* kp = ks + ((size_t)b * 128 + cj) * 512;
    const float* qe = peq + ci * 512;
    const float* ke = pek + cj * 512;
    float s = 0.f;
    for (int n = 0; n < 512; ++n) {
        float qv = qp[n] * (1.f / 512.f) + qe[n];
        float kv = kp[n] * (1.f / 512.f) + ke[n];
        s += qv * kv;
    }
    s *= 0.0441941738241592203f;   // 1/sqrt(512)
    P[i][j] = s;
    __syncthreads();
    if (tid < 16) {
        float mx = -1e30f;
        #pragma unroll
        for (int jj = 0; jj < 16; ++jj) mx = fmaxf(mx, P[tid][jj]);
        float e[16];
        float sum = 0.f;
        #pragma unroll
        for (int jj = 0; jj < 16; ++jj) { e[jj] = expf(P[tid][jj] - mx); sum += e[jj]; }
        float inv = 1.f / sum;
        #pragma unroll
        for (int jj = 0; jj < 16; ++jj) P[tid][jj] = e[jj] * inv;
    }
    __syncthreads();
    for (int idx = tid; idx < 16 * 512; idx += 256) {
        int ii = idx >> 9, n = idx & 511;
        const float* vb = vs + ((size_t)b * 128 + head * 16) * 512 + n;
        float acc = 0.f;
        #pragma unroll
        for (int jj = 0; jj < 16; ++jj) acc += P[ii][jj] * vb[jj * 512] * (1.f / 512.f);
        out[((size_t)b * 128 + head * 16 + ii) * 512 + n] = acc;
    }
}

// ---------------- setup: shuffled pw weights -> bf16 ----------------
__global__ __launch_bounds__(256) void k_wsetup(const float* __restrict__ pww,
                                                unsigned short* __restrict__ wsh) {
    int tid = blockIdx.x * 256 + threadIdx.x;
    if (tid >= 64 * 320) return;
    int m = tid / 320, src = tid % 320;
    int o = (src % 5) * 64 + src / 5;     // shuffled-channel index fed by cat channel `src`
    wsh[m * 320 + src] = f2bf(pww[m * 320 + o]);
}

// ---------------- K7: fused shuffle + dw3x3(320) + GELU + sliced-K MFMA pw 320->64 + GELU ----
// Block = 1 row x 64 cols. K streamed in 32-wide slices: 6 chunks of 32 staged planes;
// each chunk emits 1 (x) or 2 (v: attn / plain) B-slices consumed immediately by MFMA.
// LDS 39.3 KB -> 4 blocks/CU.
__global__ __launch_bounds__(256, 4) void k_proj2(
    const float* __restrict__ x, const float* __restrict__ v,
    const float* __restrict__ arow, const float* __restrict__ acol,
    const float* __restrict__ aprw, const float* __restrict__ apcw,
    const float* __restrict__ dww, const float* __restrict__ dwb,
    const unsigned short* __restrict__ wsh, const float* __restrict__ pwb,
    float* __restrict__ out)
{
    __shared__ float stage[32][3][67];        // 25,728 B
    __shared__ unsigned short Bt[64][40];     // 5,120 B  (row 80 B, 16B-aligned units)
    __shared__ float avec[32][66];            // 8,448 B  (attn map window per v-chunk)
    int tid = threadIdx.x;
    int lane = tid & 63, wva = tid >> 6;
    int px = lane;
    int w0 = blockIdx.x * 64;
    int h  = blockIdx.y;
    int b  = blockIdx.z;
    const float* xb = x + (size_t)b * 64 * PLANE;
    const float* vb = v + (size_t)b * 128 * PLANE;
    const float* arb = arow + (size_t)b * 128 * 512;
    const float* acb = acol + (size_t)b * 128 * 512;

    // A-fragments (pw weights), held in VGPRs for the whole kernel.
    bf16x8 afrag[10];
    {
        const unsigned short* wp = wsh + (size_t)(wva * 16 + (lane & 15)) * 320 + ((lane >> 4) * 8);
        #pragma unroll
        for (int ks = 0; ks < 10; ++ks)
            afrag[ks] = *(const bf16x8*)(wp + ks * 32);
    }
    f32x4 acc[4];
    #pragma unroll
    for (int pt = 0; pt < 4; ++pt) acc[pt] = (f32x4){0.f, 0.f, 0.f, 0.f};

    float vr0 = (h >= 1)   ? 1.f : 0.f;
    float vr2 = (h <= 510) ? 1.f : 0.f;

    for (int chunk = 0; chunk < 6; ++chunk) {
        int p0 = chunk * 32;                 // plane base: 0..63 = x, 64..191 = v channel p-64
        bool isv = (p0 >= 64);
        __syncthreads();
        // stage 32 planes x 3 rows x 66 cols (zero-fill = conv zero padding)
        for (int i = tid; i < 32 * 198; i += 256) {
            int pl = i / 198;
            int rem = i - pl * 198;
            int rr = rem / 66, cc = rem - rr * 66;
            int plane = p0 + pl;
            int hh = h + rr - 1, ww = w0 + cc - 1;
            float val = 0.f;
            if (hh >= 0 && hh < 512 && ww >= 0 && ww < 512) {
                const float* sp = (plane < 64) ? (xb + (size_t)plane * PLANE)
                                               : (vb + (size_t)(plane - 64) * PLANE);
                val = sp[hh * 512 + ww];
            }
            stage[pl][rr][cc] = val;
        }
        if (isv) {
            int cbase = p0 - 64;
            for (int i = tid; i < 32 * 66; i += 256) {
                int cl = i / 66, wloc = i - cl * 66;
                int c = cbase + cl;
                int ww = w0 + wloc - 1;
                float val = 0.f;
                if (ww >= 0 && ww < 512)
                    val = aprw[c] * arb[(size_t)c * 512 + ww]
                        + apcw[c] * acb[(size_t)c * 512 + ww];
                avec[cl][wloc] = val;
            }
        }
        __syncthreads();
        // conv pass 1: x chunk -> src = plane; v chunk -> src = 64 + c (attn folded in)
        {
            bf16x8 res;
            #pragma unroll
            for (int sub = 0; sub < 8; ++sub) {
                int pl = wva * 8 + sub;
                int src = p0 + pl;                       // x chunks
                if (isv) src = 64 + (p0 - 64) + pl;      // v attn channels
                int o = (src % 5) * 64 + src / 5;
                const float* wt = dww + o * 9;
                float conv = dwb[o];
                #pragma unroll
                for (int rr = 0; rr < 3; ++rr)
                    #pragma unroll
                    for (int dc = 0; dc < 3; ++dc)
                        conv += wt[rr * 3 + dc] * stage[pl][rr][px + dc];
                if (isv) {
                    #pragma unroll
                    for (int dc = 0; dc < 3; ++dc) {
                        float wsum = wt[dc] * vr0 + wt[3 + dc] + wt[6 + dc] * vr2;
                        conv += wsum * avec[pl][px + dc];
                    }
                }
                res[sub] = (short)f2bf(gelu_f(conv));
            }
            *(bf16x8*)&Bt[px][wva * 8] = res;
        }
        __syncthreads();
        {
            int ks = chunk;                  // slice index: x chunks 0,1; v-attn 2..5
            #pragma unroll
            for (int pt = 0; pt < 4; ++pt) {
                bf16x8 bfrag = *(const bf16x8*)&Bt[pt * 16 + (lane & 15)][(lane >> 4) * 8];
                acc[pt] = __builtin_amdgcn_mfma_f32_16x16x32_bf16(afrag[ks], bfrag, acc[pt], 0, 0, 0);
            }
        }
        if (isv) {
            __syncthreads();
            // conv pass 2: plain conv of v, src = 192 + c
            bf16x8 res;
            #pragma unroll
            for (int sub = 0; sub < 8; ++sub) {
                int pl = wva * 8 + sub;
                int src = 192 + (p0 - 64) + pl;
                int o = (src % 5) * 64 + src / 5;
                const float* wt = dww + o * 9;
                float conv = dwb[o];
                #pragma unroll
                for (int rr = 0; rr < 3; ++rr)
                    #pragma unroll
                    for (int dc = 0; dc < 3; ++dc)
                        conv += wt[rr * 3 + dc] * stage[pl][rr][px + dc];
                res[sub] = (short)f2bf(gelu_f(conv));
            }
            *(bf16x8*)&Bt[px][wva * 8] = res;
            __syncthreads();
            int ks = chunk + 4;              // v-plain slices 6..9
            #pragma unroll
            for (int pt = 0; pt < 4; ++pt) {
                bf16x8 bfrag = *(const bf16x8*)&Bt[pt * 16 + (lane & 15)][(lane >> 4) * 8];
                acc[pt] = __builtin_amdgcn_mfma_f32_16x16x32_bf16(afrag[ks], bfrag, acc[pt], 0, 0, 0);
            }
        }
    }
    // epilogue: D col=lane&15 -> pixel, row=(lane>>4)*4+r -> m
    #pragma unroll
    for (int pt = 0; pt < 4; ++pt) {
        int pxo = pt * 16 + (lane & 15);
        #pragma unroll
        for (int r = 0; r < 4; ++r) {
            int m = wva * 16 + (lane >> 4) * 4 + r;
            out[((size_t)b * 64 + m) * PLANE + h * 512 + w0 + pxo] = gelu_f(acc[pt][r] + pwb[m]);
        }
    }
}

extern "C" void kernel_launch(void* const* d_in, const int* in_sizes, int n_in,
                              void* d_out, int out_size, void* d_ws, size_t ws_size,
                              hipStream_t stream) {
    const float* x    = (const float*)d_in[0];
    const float* sc   = (const float*)d_in[1];
    const float* lnw  = (const float*)d_in[2];
    const float* lnb  = (const float*)d_in[3];
    const float* ddw  = (const float*)d_in[4];
    const float* dbs  = (const float*)d_in[5];
    const float* dbt  = (const float*)d_in[6];
    const float* pw1  = (const float*)d_in[7];
    const float* pb1  = (const float*)d_in[8];
    const float* qdw  = (const float*)d_in[9];
    const float* qbs  = (const float*)d_in[10];
    const float* qbt  = (const float*)d_in[11];
    const float* kdw  = (const float*)d_in[12];
    const float* kbs  = (const float*)d_in[13];
    const float* kbt  = (const float*)d_in[14];
    const float* vpw  = (const float*)d_in[15];
    const float* vbs  = (const float*)d_in[16];
    const float* vbt  = (const float*)d_in[17];
    const float* pdw  = (const float*)d_in[18];
    const float* pdb  = (const float*)d_in[19];
    const float* ppw  = (const float*)d_in[20];
    const float* ppb  = (const float*)d_in[21];
    const float* perq = (const float*)d_in[22];
    const float* perk = (const float*)d_in[23];
    const float* pecq = (const float*)d_in[24];
    const float* peck = (const float*)d_in[25];
    const float* aprw = (const float*)d_in[26];
    const float* apcw = (const float*)d_in[27];

    // d_out doubles as scratch: sn (K1->K2), then k_in (K3->K4), then final out (K7).
    float* bufA = (float*)d_out;         // 33,554,432 floats
    float* ws   = (float*)d_ws;
    float* bufB = ws;                    // 33,554,432 floats: t1, later col partials
    float* bufV = ws + 33554432;         // 67,108,864 floats: v
    float* sm   = ws + 100663296;        // pooled vectors (1,048,576 floats)
    float* qrow = sm;
    float* krow = sm + 131072;
    float* vrow = sm + 262144;
    float* qcol = sm + 393216;
    float* kcol = sm + 524288;
    float* vcol = sm + 655360;
    float* arow = sm + 786432;
    float* acol = sm + 917504;
    unsigned short* wsh = (unsigned short*)(ws + 101711872);   // 20480 bf16
    float* qcp  = bufB;                  // col partials alias dead t1 buffer
    float* kcp  = bufB + 8388608;
    float* vcp  = bufB + 16777216;

    k_wsetup<<<80,    256, 0, stream>>>(ppw, wsh);
    k_ln   <<<4096,   128, 0, stream>>>(sc, lnw, lnb, bufA);
    k_dw64 <<<131072, 256, 0, stream>>>(bufA, ddw, dbs, dbt, bufB);
    k_pw_kv<<<2048,   256, 0, stream>>>(bufB, pw1, pb1, vpw, vbs, vbt, bufA, bufV);
    k_dwpool<<<8192,  512, 0, stream>>>(x,    qdw, qbs, qbt, qrow, qcp);
    k_dwpool<<<8192,  512, 0, stream>>>(bufA, kdw, kbs, kbt, krow, kcp);
    k_vpool<<<16384,  512, 0, stream>>>(bufV, vrow, vcp);
    k_colreduce<<<512, 256, 0, stream>>>(qcp, qcol, 131072);
    k_colreduce<<<512, 256, 0, stream>>>(kcp, kcol, 131072);
    k_colreduce<<<512, 256, 0, stream>>>(vcp, vcol, 131072);
    k_attn <<<32,     256, 0, stream>>>(qrow, krow, vrow, qcol, kcol, vcol,
                                        perq, perk, pecq, peck, arow, acol);
    dim3 g7(8, 512, 2);
    k_proj2<<<g7,     256, 0, stream>>>(x, bufV, arow, acol, aprw, apcw,
                                        pdw, pdb, wsh, ppb, (float*)d_out);
}